// Round 6
// baseline (480.607 us; speedup 1.0000x reference)
//
#include <hip/hip_runtime.h>
#include <hip/hip_bf16.h>
#include <stdint.h>

// Problem constants
#define T_ 4
#define B_ 32
#define C_ 512
#define N_ 256
#define HEADS_ 8

typedef __attribute__((ext_vector_type(8))) short bf16x8;      // 8 bf16 (4 VGPR) MFMA operand
typedef __attribute__((ext_vector_type(4))) float float4_;
typedef __attribute__((ext_vector_type(16))) float f32x16;     // 32x32 MFMA accumulator

__device__ __forceinline__ unsigned short f2bf(float x){       // RNE f32->bf16
  unsigned int u = __float_as_uint(x);
  u += 0x7FFFu + ((u >> 16) & 1u);
  return (unsigned short)(u >> 16);
}
__device__ __forceinline__ float bf2f(unsigned short b){
  return __uint_as_float(((unsigned int)b) << 16);
}

// async global->LDS, 16B per lane (dest = wave-uniform base + lane*16)
__device__ __forceinline__ void gload16(const void* g, void* l){
  __builtin_amdgcn_global_load_lds(
      (const __attribute__((address_space(1))) unsigned int*)g,
      (__attribute__((address_space(3))) unsigned int*)l, 16, 0, 0);
}

// fragment read from 64B-row tile (BK=32): byte = row*64 + (cb ^ (((row>>1)&3)<<4))
// 8-row groups tile all 32 banks -> throughput-optimal b128 (4 accesses/bank/wave).
__device__ __forceinline__ bf16x8 frag32(const unsigned short* base, int row, int cb){
  return *(const bf16x8*)((const char*)base + row * 64 + (cb ^ (((row >> 1) & 3) << 4)));
}

// stage one BK=32 K-slice: A (3 terms, 64 rows x 32c = 12KB) + B (256 rows x 32c = 16KB)
// linear LDS dest, inverse-swizzled global source (involution).
// wbase = weight base already offset by o0*512; term stride = 1048576 shorts (2MB).
__device__ __forceinline__ void stage_tiles(const unsigned short* wbase,
    const unsigned short* bsrc, int kk, int tid,
    unsigned short* Asb, unsigned short* Bsb)
{
  { int c = tid; int term = c >> 8; int ct = c & 255; int row = ct >> 2; int slot = ct & 3;
    const char* s = (const char*)(wbase + (size_t)term * 1048576 + (size_t)row * 512 + kk * 32)
                    + ((slot * 16) ^ (((row >> 1) & 3) << 4));
    gload16(s, (char*)Asb + c * 16); }
  if (tid < 256){
    int c = 512 + tid; int ct = c & 255; int row = ct >> 2; int slot = ct & 3;
    const char* s = (const char*)(wbase + (size_t)2 * 1048576 + (size_t)row * 512 + kk * 32)
                    + ((slot * 16) ^ (((row >> 1) & 3) << 4));
    gload16(s, (char*)Asb + c * 16); }
#pragma unroll
  for (int p = 0; p < 2; p++){
    int c = p * 512 + tid; int row = c >> 2; int slot = c & 3;
    const char* s = (const char*)(bsrc + (size_t)row * 512 + kk * 32)
                    + ((slot * 16) ^ (((row >> 1) & 3) << 4));
    gload16(s, (char*)Bsb + c * 16); }
}

// ---------------------------------------------------------------------------
// prep: fold BN into weights, split into bf16 hi+mid+lo (3-term, err <= 2^-27),
// build per-channel bias.
// ---------------------------------------------------------------------------
struct PrepArgs {
  const float* w[4];
  const float* g[4];
  const float* bb[4];
  const float* m[4];
  const float* v[4];
  const float* pbias;
};

__global__ __launch_bounds__(256) void prep_kernel(PrepArgs pa,
    unsigned short* __restrict__ whi, unsigned short* __restrict__ wmid,
    unsigned short* __restrict__ wlo, float* __restrict__ biasv)
{
  int idx = blockIdx.x * 256 + threadIdx.x;      // < 4*512*512
  int mat = idx >> 18;
  int rem = idx & 0x3FFFF;
  int o = rem >> 9;
  float g   = pa.g[mat][o];
  float var = pa.v[mat][o];
  float mm  = pa.m[mat][o];
  float bof = pa.bb[mat][o];
  float rs  = g / sqrtf(var + 1e-5f);
  float wv  = pa.w[mat][rem] * rs;
  unsigned short hi = f2bf(wv);
  float r1 = wv - bf2f(hi);
  unsigned short mid = f2bf(r1);
  float r2 = r1 - bf2f(mid);
  unsigned short lo = f2bf(r2);
  whi[idx] = hi;
  wmid[idx] = mid;
  wlo[idx] = lo;
  if ((rem & 511) == 0){
    float bias = (mat < 3) ? (bof - mm * rs) : ((pa.pbias[o] - mm) * rs + bof);
    biasv[mat * 512 + o] = bias;
  }
}

// ---------------------------------------------------------------------------
// K1: proj LIF over t (bitwise-identical fp32 ops) + transpose -> [t,b,n,c].
// ---------------------------------------------------------------------------
__global__ __launch_bounds__(256) void lif_tr_kernel(const float* __restrict__ x,
                                                     unsigned short* __restrict__ xsT)
{
  __shared__ alignas(16) unsigned short tile[64][66];
  int bid = blockIdx.x;
  int b  = bid & 31;
  int r  = bid >> 5;
  int ct = r & 7;
  int nt = r >> 3;
  int tid = threadIdx.x;
  int col = tid & 63;
  int rq  = tid >> 6;
  float v[16];
#pragma unroll
  for (int i = 0; i < 16; i++) v[i] = 0.0f;
  const float* xb = x + (size_t)b * C_ * N_ + (size_t)ct * 64 * N_ + nt * 64;
  unsigned short* ob = xsT + (size_t)b * N_ * C_ + (size_t)nt * 64 * C_ + ct * 64;
  for (int t = 0; t < T_; t++){
    const float* xt = xb + (size_t)t * B_ * C_ * N_;
#pragma unroll
    for (int i = 0; i < 16; i++){
      int row = i * 4 + rq;
      float xx = xt[(size_t)row * N_ + col];
      float vv = v[i];
      vv = vv + (xx - vv) * 0.5f;
      bool sp = (vv - 1.0f) >= 0.0f;
      tile[row][col] = sp ? 0x3F80 : 0;
      v[i] = sp ? 0.0f : vv;
    }
    __syncthreads();
    unsigned short* ot = ob + (size_t)t * B_ * N_ * C_;
#pragma unroll
    for (int p = 0; p < 2; p++){
      int nrow = p * 32 + (tid >> 3);
      int c0   = (tid & 7) * 8;
      unsigned int w0 = (unsigned int)tile[c0 + 0][nrow] | ((unsigned int)tile[c0 + 1][nrow] << 16);
      unsigned int w1 = (unsigned int)tile[c0 + 2][nrow] | ((unsigned int)tile[c0 + 3][nrow] << 16);
      unsigned int w2 = (unsigned int)tile[c0 + 4][nrow] | ((unsigned int)tile[c0 + 5][nrow] << 16);
      unsigned int w3 = (unsigned int)tile[c0 + 6][nrow] | ((unsigned int)tile[c0 + 7][nrow] << 16);
      uint4 v4{w0, w1, w2, w3};
      *(uint4*)(ot + (size_t)nrow * C_ + c0) = v4;
    }
    __syncthreads();
  }
}

// ---------------------------------------------------------------------------
// K2: q/k/v branch: y = W'.xs (+bias) -> LIF (vth=1) -> spikes.
// 512 threads (8 waves), wave tile [32o][64n]; BK=32, full LDS double-buffer,
// prefetch-next-before-compute (T3 minimum-2-phase). Numerically identical
// accumulation order to the BK=64 version.
// ---------------------------------------------------------------------------
__global__ __launch_bounds__(512, 4) void branch_kernel(
    const unsigned short* __restrict__ whi,
    const float* __restrict__ biasv, const unsigned short* __restrict__ xsT,
    unsigned short* __restrict__ qT, unsigned short* __restrict__ kS,
    unsigned short* __restrict__ vS)
{
  __shared__ alignas(16) unsigned short As[2][3 * 2048];   // 2 x 12KB
  __shared__ alignas(16) unsigned short Bs[2][8192];       // 2 x 16KB (also bounce)
  __shared__ alignas(16) float bias_lds[64];

  int bid = blockIdx.x;
  int b  = bid & 31;          // b fastest -> XCD/L2 locality on xsT
  int r2 = bid >> 5;
  int ot = r2 & 7;
  int br = r2 >> 3;           // 0=q 1=k 2=v
  int o0 = ot * 64;
  int tid = threadIdx.x;
  int wv   = tid >> 6;        // wave 0..7
  int wr   = wv >> 2;         // o half (32 rows)
  int wc   = wv & 3;          // n quarter (64 cols)
  int lane = tid & 63;
  int lm = lane & 31;
  int hi = lane >> 5;

  if (tid < 64) bias_lds[tid] = biasv[br * 512 + o0 + tid];

  const unsigned short* wbase = whi + (size_t)br * 262144 + (size_t)o0 * 512;

  f32x16 acc[2];
  float  st[2][16];
#pragma unroll
  for (int c = 0; c < 2; c++)
#pragma unroll
    for (int i = 0; i < 16; i++) st[c][i] = 0.0f;

  for (int t = 0; t < T_; t++){
#pragma unroll
    for (int c = 0; c < 2; c++)
#pragma unroll
      for (int i = 0; i < 16; i++) acc[c][i] = 0.0f;

    const unsigned short* bsrc = xsT + (size_t)(t * B_ + b) * N_ * C_;

    stage_tiles(wbase, bsrc, 0, tid, As[0], Bs[0]);
    __syncthreads();

    for (int kk = 0; kk < 16; kk++){            // K = 16 * 32
      int cur = kk & 1;
      if (kk < 15) stage_tiles(wbase, bsrc, kk + 1, tid, As[cur ^ 1], Bs[cur ^ 1]);
#pragma unroll
      for (int ks = 0; ks < 2; ks++){
        int cb = ks * 32 + 16 * hi;
        bf16x8 b0 = frag32(Bs[cur], wc * 64 + lm,      cb);
        bf16x8 b1 = frag32(Bs[cur], wc * 64 + 32 + lm, cb);
        bf16x8 a0 = frag32(As[cur] + 0 * 2048, wr * 32 + lm, cb);
        acc[0] = __builtin_amdgcn_mfma_f32_32x32x16_bf16(a0, b0, acc[0], 0, 0, 0);
        acc[1] = __builtin_amdgcn_mfma_f32_32x32x16_bf16(a0, b1, acc[1], 0, 0, 0);
        bf16x8 a1 = frag32(As[cur] + 1 * 2048, wr * 32 + lm, cb);
        acc[0] = __builtin_amdgcn_mfma_f32_32x32x16_bf16(a1, b0, acc[0], 0, 0, 0);
        acc[1] = __builtin_amdgcn_mfma_f32_32x32x16_bf16(a1, b1, acc[1], 0, 0, 0);
        bf16x8 a2 = frag32(As[cur] + 2 * 2048, wr * 32 + lm, cb);
        acc[0] = __builtin_amdgcn_mfma_f32_32x32x16_bf16(a2, b0, acc[0], 0, 0, 0);
        acc[1] = __builtin_amdgcn_mfma_f32_32x32x16_bf16(a2, b1, acc[1], 0, 0, 0);
      }
      __syncthreads();                          // next-tile loads landed; reads done
    }

    // epilogue: bias + LIF -> spike bits into bounce (Bs region, 32KB)
    unsigned short* bounce = (unsigned short*)Bs;
#pragma unroll
    for (int nf = 0; nf < 2; nf++){
      int n_loc = wc * 64 + nf * 32 + lm;
#pragma unroll
      for (int rq = 0; rq < 4; rq++){
        float4_ b4 = *(const float4_*)&bias_lds[wr * 32 + 8 * rq + 4 * hi];
        unsigned short sb[4];
#pragma unroll
        for (int rr = 0; rr < 4; rr++){
          int r = rq * 4 + rr;
          float y = acc[nf][r] + b4[rr];
          float vvv = st[nf][r];
          vvv = vvv + (y - vvv) * 0.5f;
          bool sp = (vvv - 1.0f) >= 0.0f;
          st[nf][r] = sp ? 0.0f : vvv;
          sb[rr] = sp ? 0x3F80 : 0;
        }
        if (br == 0){   // q bounce: [n][64o] swizzled 128B rows, b64 pack
          unsigned int u0 = (unsigned int)sb[0] | ((unsigned int)sb[1] << 16);
          unsigned int u1 = (unsigned int)sb[2] | ((unsigned int)sb[3] << 16);
          int o0b = (wr * 32 + 8 * rq + 4 * hi) * 2;
          *(unsigned long long*)((char*)bounce + n_loc * 128 + (o0b ^ ((n_loc & 7) << 4)))
              = ((unsigned long long)u1 << 32) | u0;
        } else {        // k/v bounce: [64o][256n] linear
#pragma unroll
          for (int rr = 0; rr < 4; rr++){
            int o_loc = wr * 32 + rr + 8 * rq + 4 * hi;
            *(unsigned short*)((char*)bounce + o_loc * 512 + n_loc * 2) = sb[rr];
          }
        }
      }
    }
    __syncthreads();
    if (br == 0){
      unsigned short* dst = qT + (size_t)(t * B_ + b) * N_ * C_ + o0;
#pragma unroll
      for (int p = 0; p < 4; p++){
        int chunk = p * 512 + tid;
        int row = chunk >> 3, cbq = (chunk & 7) * 16;
        uint4 val = *(const uint4*)((const char*)bounce + row * 128 + (cbq ^ ((row & 7) << 4)));
        *(uint4*)((char*)dst + (size_t)row * 1024 + cbq) = val;
      }
    } else {
      unsigned short* dst = (br == 1 ? kS : vS) + ((size_t)(t * B_ + b) * C_ + o0) * N_;
#pragma unroll
      for (int p = 0; p < 4; p++){
        int chunk = p * 512 + tid;
        int row = chunk >> 5, nb = (chunk & 31) * 16;
        uint4 val = *(const uint4*)((const char*)bounce + row * 512 + nb);
        *(uint4*)((char*)dst + (size_t)row * 512 + nb) = val;
      }
    }
    __syncthreads();   // bounce reads done before next t's STAGE overwrites
  }
}

// ---------------------------------------------------------------------------
// K3: per (b,h): kv = K.V^T (exact integers), a = Q.kv * 0.125, attn LIF
// (vth=0.5, dyadic-exact) -> spikes to sT [t,b,n,c]. (unchanged)
// ---------------------------------------------------------------------------
__device__ __forceinline__ bf16x8 lds_frag(const unsigned short* base, int row, int cb){
  return *(const bf16x8*)((const char*)base + row * 128 + (cb ^ ((row & 7) << 4)));
}

__global__ __launch_bounds__(256, 2) void attn_kernel(
    const unsigned short* __restrict__ qT, const unsigned short* __restrict__ kS,
    const unsigned short* __restrict__ vS, unsigned short* __restrict__ sT)
{
  __shared__ alignas(16) unsigned short Ks[64 * 64];
  __shared__ alignas(16) unsigned short Vs[64 * 64];
  __shared__ alignas(16) unsigned short KVT[64 * 64];
  __shared__ alignas(16) unsigned short Qs[256 * 64];

  int bid = blockIdx.x;
  int b = bid & 31;
  int h = bid >> 5;
  int tid = threadIdx.x;
  int w = tid >> 6;
  int lane = tid & 63;
  int lm = lane & 31, hi = lane >> 5;
  int mfk = w >> 1, nfk = w & 1;

  float stA[2][2][16];
#pragma unroll
  for (int a = 0; a < 2; a++)
#pragma unroll
  for (int c = 0; c < 2; c++)
#pragma unroll
  for (int i = 0; i < 16; i++) stA[a][c][i] = 0.0f;

  for (int t = 0; t < T_; t++){
    const unsigned short* ksrc = kS + ((size_t)(t * B_ + b) * C_ + h * 64) * N_;
    const unsigned short* vsrc = vS + ((size_t)(t * B_ + b) * C_ + h * 64) * N_;
    const unsigned short* qsrc = qT + (size_t)(t * B_ + b) * N_ * C_ + h * 64;
    unsigned short* sdst = sT + (size_t)(t * B_ + b) * N_ * C_ + h * 64;

    f32x16 kvacc;
#pragma unroll
    for (int i = 0; i < 16; i++) kvacc[i] = 0.0f;

    for (int ch = 0; ch < 4; ch++){
      __syncthreads();
#pragma unroll
      for (int p = 0; p < 2; p++){
        int chunk = p * 256 + tid;
        int row = chunk >> 3, cb = (chunk & 7) * 16;
        int so = (cb ^ ((row & 7) << 4));
        gload16((const char*)ksrc + (size_t)row * 512 + ch * 128 + so, (char*)Ks + chunk * 16);
        gload16((const char*)vsrc + (size_t)row * 512 + ch * 128 + so, (char*)Vs + chunk * 16);
      }
      __syncthreads();
#pragma unroll
      for (int ki = 0; ki < 4; ki++){
        int cb = ki * 32 + 16 * hi;
        bf16x8 ak = lds_frag(Ks, mfk * 32 + lm, cb);
        bf16x8 bv = lds_frag(Vs, nfk * 32 + lm, cb);
        kvacc = __builtin_amdgcn_mfma_f32_32x32x16_bf16(ak, bv, kvacc, 0, 0, 0);
      }
    }
    {
      int e = nfk * 32 + lm;
#pragma unroll
      for (int rq = 0; rq < 4; rq++){
        unsigned int u0 = (unsigned int)f2bf(kvacc[rq * 4 + 0])
                        | ((unsigned int)f2bf(kvacc[rq * 4 + 1]) << 16);
        unsigned int u1 = (unsigned int)f2bf(kvacc[rq * 4 + 2])
                        | ((unsigned int)f2bf(kvacc[rq * 4 + 3]) << 16);
        int d0b = (mfk * 32 + 8 * rq + 4 * hi) * 2;
        *(unsigned long long*)((char*)KVT + e * 128 + (d0b ^ ((e & 7) << 4)))
            = ((unsigned long long)u1 << 32) | u0;
      }
    }
#pragma unroll
    for (int p = 0; p < 8; p++){
      int chunk = p * 256 + tid;
      int row = chunk >> 3, cb = (chunk & 7) * 16;
      gload16((const char*)qsrc + (size_t)row * 1024 + (cb ^ ((row & 7) << 4)),
              (char*)Qs + chunk * 16);
    }
    __syncthreads();
    f32x16 aacc[2][2];
#pragma unroll
    for (int a = 0; a < 2; a++)
#pragma unroll
    for (int c = 0; c < 2; c++)
#pragma unroll
    for (int i = 0; i < 16; i++) aacc[a][c][i] = 0.0f;
#pragma unroll
    for (int ki = 0; ki < 4; ki++){
      int cb = ki * 32 + 16 * hi;
      bf16x8 aq0 = lds_frag(Qs, w * 64 + lm,      cb);
      bf16x8 aq1 = lds_frag(Qs, w * 64 + 32 + lm, cb);
      bf16x8 b0  = lds_frag(KVT, lm,      cb);
      bf16x8 b1  = lds_frag(KVT, 32 + lm, cb);
      aacc[0][0] = __builtin_amdgcn_mfma_f32_32x32x16_bf16(aq0, b0, aacc[0][0], 0, 0, 0);
      aacc[0][1] = __builtin_amdgcn_mfma_f32_32x32x16_bf16(aq0, b1, aacc[0][1], 0, 0, 0);
      aacc[1][0] = __builtin_amdgcn_mfma_f32_32x32x16_bf16(aq1, b0, aacc[1][0], 0, 0, 0);
      aacc[1][1] = __builtin_amdgcn_mfma_f32_32x32x16_bf16(aq1, b1, aacc[1][1], 0, 0, 0);
    }
#pragma unroll
    for (int mf = 0; mf < 2; mf++){
#pragma unroll
      for (int nf = 0; nf < 2; nf++){
        int e_loc = nf * 32 + lm;
#pragma unroll
        for (int r = 0; r < 16; r++){
          float aval = aacc[mf][nf][r] * 0.125f;
          float vvv = stA[mf][nf][r];
          vvv = vvv + (aval - vvv) * 0.5f;
          bool sp = (vvv - 0.5f) >= 0.0f;
          stA[mf][nf][r] = sp ? 0.0f : vvv;
          int n_loc = w * 64 + mf * 32 + (r & 3) + 8 * (r >> 2) + 4 * hi;
          *(unsigned short*)((char*)Qs + n_loc * 128 + ((e_loc * 2) ^ ((n_loc & 7) << 4))) = sp ? 0x3F80 : 0;
        }
      }
    }
    __syncthreads();
#pragma unroll
    for (int p = 0; p < 8; p++){
      int chunk = p * 256 + tid;
      int row = chunk >> 3, cb = (chunk & 7) * 16;
      uint4 val = *(const uint4*)((const char*)Qs + row * 128 + (cb ^ ((row & 7) << 4)));
      *(uint4*)((char*)sdst + (size_t)row * 1024 + cb) = val;
    }
  }
}

// ---------------------------------------------------------------------------
// K4: projection: out = W'p . s + bias'p. Same 512-thread BK=32 dbuf template.
// ---------------------------------------------------------------------------
__global__ __launch_bounds__(512, 4) void proj_kernel(
    const unsigned short* __restrict__ whi,
    const float* __restrict__ biasv, const unsigned short* __restrict__ sT,
    float* __restrict__ out)
{
  __shared__ alignas(16) unsigned short As[2][3 * 2048];
  __shared__ alignas(16) unsigned short Bs[2][8192];
  __shared__ alignas(16) float bias_lds[64];

  int bid = blockIdx.x;
  int tb = bid & 127;
  int ot = bid >> 7;
  int t = tb >> 5, b = tb & 31;
  int o0 = ot * 64;
  int tid = threadIdx.x;
  int wv = tid >> 6, wr = wv >> 2, wc = wv & 3;
  int lane = tid & 63, lm = lane & 31, hi = lane >> 5;

  if (tid < 64) bias_lds[tid] = biasv[3 * 512 + o0 + tid];

  const unsigned short* wbase = whi + (size_t)3 * 262144 + (size_t)o0 * 512;
  const unsigned short* bsrc = sT + (size_t)(t * B_ + b) * N_ * C_;

  f32x16 acc[2];
#pragma unroll
  for (int c = 0; c < 2; c++)
#pragma unroll
    for (int i = 0; i < 16; i++) acc[c][i] = 0.0f;

  stage_tiles(wbase, bsrc, 0, tid, As[0], Bs[0]);
  __syncthreads();

  for (int kk = 0; kk < 16; kk++){
    int cur = kk & 1;
    if (kk < 15) stage_tiles(wbase, bsrc, kk + 1, tid, As[cur ^ 1], Bs[cur ^ 1]);
#pragma unroll
    for (int ks = 0; ks < 2; ks++){
      int cb = ks * 32 + 16 * hi;
      bf16x8 b0 = frag32(Bs[cur], wc * 64 + lm,      cb);
      bf16x8 b1 = frag32(Bs[cur], wc * 64 + 32 + lm, cb);
      bf16x8 a0 = frag32(As[cur] + 0 * 2048, wr * 32 + lm, cb);
      acc[0] = __builtin_amdgcn_mfma_f32_32x32x16_bf16(a0, b0, acc[0], 0, 0, 0);
      acc[1] = __builtin_amdgcn_mfma_f32_32x32x16_bf16(a0, b1, acc[1], 0, 0, 0);
      bf16x8 a1 = frag32(As[cur] + 1 * 2048, wr * 32 + lm, cb);
      acc[0] = __builtin_amdgcn_mfma_f32_32x32x16_bf16(a1, b0, acc[0], 0, 0, 0);
      acc[1] = __builtin_amdgcn_mfma_f32_32x32x16_bf16(a1, b1, acc[1], 0, 0, 0);
      bf16x8 a2 = frag32(As[cur] + 2 * 2048, wr * 32 + lm, cb);
      acc[0] = __builtin_amdgcn_mfma_f32_32x32x16_bf16(a2, b0, acc[0], 0, 0, 0);
      acc[1] = __builtin_amdgcn_mfma_f32_32x32x16_bf16(a2, b1, acc[1], 0, 0, 0);
    }
    __syncthreads();
  }

  float* dst = out + ((size_t)(t * B_ + b) * C_ + o0) * N_;
#pragma unroll
  for (int nf = 0; nf < 2; nf++){
    int n_loc = wc * 64 + nf * 32 + lm;
#pragma unroll
    for (int rq = 0; rq < 4; rq++){
      float4_ b4 = *(const float4_*)&bias_lds[wr * 32 + 8 * rq + 4 * hi];
#pragma unroll
      for (int rr = 0; rr < 4; rr++){
        int o_loc = wr * 32 + rr + 8 * rq + 4 * hi;
        dst[(size_t)o_loc * N_ + n_loc] = acc[nf][rq * 4 + rr] + b4[rr];
      }
    }
  }
}

// ---------------------------------------------------------------------------
// launch
// ---------------------------------------------------------------------------
extern "C" void kernel_launch(void* const* d_in, const int* in_sizes, int n_in,
                              void* d_out, int out_size, void* d_ws, size_t ws_size,
                              hipStream_t stream) {
  const float* x = (const float*)d_in[0];
  PrepArgs pa;
  pa.w[0]  = (const float*)d_in[1];
  pa.g[0]  = (const float*)d_in[2];
  pa.bb[0] = (const float*)d_in[3];
  pa.m[0]  = (const float*)d_in[4];
  pa.v[0]  = (const float*)d_in[5];
  pa.w[1]  = (const float*)d_in[6];
  pa.g[1]  = (const float*)d_in[7];
  pa.bb[1] = (const float*)d_in[8];
  pa.m[1]  = (const float*)d_in[9];
  pa.v[1]  = (const float*)d_in[10];
  pa.w[2]  = (const float*)d_in[11];
  pa.g[2]  = (const float*)d_in[12];
  pa.bb[2] = (const float*)d_in[13];
  pa.m[2]  = (const float*)d_in[14];
  pa.v[2]  = (const float*)d_in[15];
  pa.w[3]  = (const float*)d_in[16];
  pa.pbias = (const float*)d_in[17];
  pa.g[3]  = (const float*)d_in[18];
  pa.bb[3] = (const float*)d_in[19];
  pa.m[3]  = (const float*)d_in[20];
  pa.v[3]  = (const float*)d_in[21];

  // workspace layout (~140 MB). whi/wmid/wlo MUST stay 0x200000 apart
  // (stage_tiles derives term pointers arithmetically).
  char* ws = (char*)d_ws;
  unsigned short* whi  = (unsigned short*)(ws);                               // 2 MB
  unsigned short* wmid = (unsigned short*)(ws + 0x200000);                    // 2 MB
  unsigned short* wlo  = (unsigned short*)(ws + 0x400000);                    // 2 MB
  float*          biasv= (float*)(ws + 0x600000);                             // 8 KB
  unsigned short* xsT  = (unsigned short*)(ws + 0x610000);                    // 32 MiB [t,b,n,c]
  unsigned short* sTp  = xsT;                                                 // alias: xs dead before s written
  unsigned short* qT   = (unsigned short*)(ws + 0x610000 + (size_t)32*1024*1024);
  unsigned short* kS   = (unsigned short*)(ws + 0x610000 + (size_t)64*1024*1024);
  unsigned short* vS   = (unsigned short*)(ws + 0x610000 + (size_t)96*1024*1024);

  prep_kernel<<<4096, 256, 0, stream>>>(pa, whi, wmid, wlo, biasv);
  lif_tr_kernel<<<1024, 256, 0, stream>>>(x, xsT);
  branch_kernel<<<768, 512, 0, stream>>>(whi, biasv, xsT, qT, kS, vS);
  attn_kernel<<<256, 256, 0, stream>>>(qT, kS, vS, sTp);
  proj_kernel<<<1024, 512, 0, stream>>>(whi, biasv, sTp, (float*)d_out);
}

// Round 7
// 415.029 us; speedup vs baseline: 1.1580x; 1.1580x over previous
//
#include <hip/hip_runtime.h>
#include <hip/hip_bf16.h>
#include <stdint.h>

// Problem constants
#define T_ 4
#define B_ 32
#define C_ 512
#define N_ 256
#define HEADS_ 8

typedef __attribute__((ext_vector_type(8))) short bf16x8;      // 8 bf16 (4 VGPR) MFMA operand
typedef __attribute__((ext_vector_type(4))) float float4_;
typedef __attribute__((ext_vector_type(16))) float f32x16;     // 32x32 MFMA accumulator

__device__ __forceinline__ unsigned short f2bf(float x){       // RNE f32->bf16
  unsigned int u = __float_as_uint(x);
  u += 0x7FFFu + ((u >> 16) & 1u);
  return (unsigned short)(u >> 16);
}
__device__ __forceinline__ float bf2f(unsigned short b){
  return __uint_as_float(((unsigned int)b) << 16);
}

// async global->LDS, 16B per lane (dest = wave-uniform base + lane*16)
__device__ __forceinline__ void gload16(const void* g, void* l){
  __builtin_amdgcn_global_load_lds(
      (const __attribute__((address_space(1))) unsigned int*)g,
      (__attribute__((address_space(3))) unsigned int*)l, 16, 0, 0);
}

// swizzle of the 64B-row tile image (BK=32): byte = row*64 + (cb ^ swz(row))
__device__ __forceinline__ int swz32(int row){ return ((row >> 1) & 3) << 4; }

// fragment read from 64B-row tile (4 accesses/bank/wave = b128 inherent level)
__device__ __forceinline__ bf16x8 frag32(const unsigned short* base, int row, int cb){
  return *(const bf16x8*)((const char*)base + row * 64 + (cb ^ swz32(row)));
}

// ---------------------------------------------------------------------------
// stage one BK=32 K-slice from CONTIGUOUS pre-swizzled slabs:
//   A: 3 terms x 4KB slab each (term stride 0x100000 shorts = 2MB buffers)
//   B: one 16KB slab
// All sources linear -> dense full-line HBM fetches. LDS dest linear.
// ---------------------------------------------------------------------------
__device__ __forceinline__ void stage_tiles(const unsigned short* wtile,
    const unsigned short* xslab, int kk, int tid,
    unsigned short* Asb, unsigned short* Bsb)
{
  { int c = tid; int term = c >> 8; int ct = c & 255;                    // terms 0,1
    gload16((const char*)(wtile + (size_t)term * 0x100000) + kk * 4096 + ct * 16,
            (char*)Asb + c * 16); }
  if (tid < 256){                                                         // term 2
    gload16((const char*)(wtile + (size_t)2 * 0x100000) + kk * 4096 + tid * 16,
            (char*)Asb + (512 + tid) * 16); }
#pragma unroll
  for (int p = 0; p < 2; p++){
    int c = p * 512 + tid;
    gload16((const char*)xslab + kk * 16384 + c * 16, (char*)Bsb + c * 16);
  }
}

// ---------------------------------------------------------------------------
// prep: fold BN into weights, 3-term bf16 split (err <= 2^-27), write slabs
// [mat][ot][kk][4KB] with the frag32 swizzle pre-baked. One thread = 8 c.
// ---------------------------------------------------------------------------
struct PrepArgs {
  const float* w[4];
  const float* g[4];
  const float* bb[4];
  const float* m[4];
  const float* v[4];
  const float* pbias;
};

__global__ __launch_bounds__(256) void prep_kernel(PrepArgs pa,
    unsigned short* __restrict__ whi, unsigned short* __restrict__ wmid,
    unsigned short* __restrict__ wlo, float* __restrict__ biasv)
{
  int idx = blockIdx.x * 256 + threadIdx.x;      // < 4*512*64 = 131072
  int mat = idx >> 15;
  int rem = idx & 0x7FFF;
  int o   = rem >> 6;        // 0..511
  int s16 = rem & 63;        // 16B granule: kk*4 + slot
  int kk = s16 >> 2, slot = s16 & 3;
  int c0 = kk * 32 + slot * 8;

  float g   = pa.g[mat][o];
  float var = pa.v[mat][o];
  float mm  = pa.m[mat][o];
  float bof = pa.bb[mat][o];
  float rs  = g / sqrtf(var + 1e-5f);

  const float* wrow = pa.w[mat] + (size_t)o * 512 + c0;
  unsigned int h01 = 0, h23 = 0, h45 = 0, h67 = 0;
  unsigned int m01 = 0, m23 = 0, m45 = 0, m67 = 0;
  unsigned int l01 = 0, l23 = 0, l45 = 0, l67 = 0;
  unsigned short hh[8], mmv[8], ll[8];
#pragma unroll
  for (int j = 0; j < 8; j++){
    float wv = wrow[j] * rs;
    unsigned short hi = f2bf(wv);
    float r1 = wv - bf2f(hi);
    unsigned short mid = f2bf(r1);
    float r2 = r1 - bf2f(mid);
    hh[j] = hi; mmv[j] = mid; ll[j] = f2bf(r2);
  }
  h01 = (unsigned int)hh[0] | ((unsigned int)hh[1] << 16);
  h23 = (unsigned int)hh[2] | ((unsigned int)hh[3] << 16);
  h45 = (unsigned int)hh[4] | ((unsigned int)hh[5] << 16);
  h67 = (unsigned int)hh[6] | ((unsigned int)hh[7] << 16);
  m01 = (unsigned int)mmv[0] | ((unsigned int)mmv[1] << 16);
  m23 = (unsigned int)mmv[2] | ((unsigned int)mmv[3] << 16);
  m45 = (unsigned int)mmv[4] | ((unsigned int)mmv[5] << 16);
  m67 = (unsigned int)mmv[6] | ((unsigned int)mmv[7] << 16);
  l01 = (unsigned int)ll[0] | ((unsigned int)ll[1] << 16);
  l23 = (unsigned int)ll[2] | ((unsigned int)ll[3] << 16);
  l45 = (unsigned int)ll[4] | ((unsigned int)ll[5] << 16);
  l67 = (unsigned int)ll[6] | ((unsigned int)ll[7] << 16);

  int row = o & 63;
  size_t byte = (size_t)(mat * 8 + (o >> 6)) * 65536 + (size_t)kk * 4096
              + row * 64 + ((slot * 16) ^ swz32(row));
  *(uint4*)((char*)whi  + byte) = uint4{h01, h23, h45, h67};
  *(uint4*)((char*)wmid + byte) = uint4{m01, m23, m45, m67};
  *(uint4*)((char*)wlo  + byte) = uint4{l01, l23, l45, l67};

  if (s16 == 0){
    float bias = (mat < 3) ? (bof - mm * rs) : ((pa.pbias[o] - mm) * rs + bof);
    biasv[mat * 512 + o] = bias;
  }
}

// ---------------------------------------------------------------------------
// K1: proj LIF over t (bitwise-identical fp32 ops) + transpose into tiled
// slabs xsT[t][b][kk16][16KB] with frag32 swizzle pre-baked.
// ---------------------------------------------------------------------------
__global__ __launch_bounds__(256) void lif_tr_kernel(const float* __restrict__ x,
                                                     unsigned short* __restrict__ xsT)
{
  __shared__ alignas(16) unsigned short tile[64][66];
  int bid = blockIdx.x;
  int b  = bid & 31;
  int r  = bid >> 5;
  int ct = r & 7;        // c tile (64) -> kk pair {2ct, 2ct+1}
  int nt = r >> 3;       // n tile (64)
  int tid = threadIdx.x;
  int col = tid & 63;
  int rq  = tid >> 6;
  float v[16];
#pragma unroll
  for (int i = 0; i < 16; i++) v[i] = 0.0f;
  const float* xb = x + (size_t)b * C_ * N_ + (size_t)ct * 64 * N_ + nt * 64;
  for (int t = 0; t < T_; t++){
    const float* xt = xb + (size_t)t * B_ * C_ * N_;
#pragma unroll
    for (int i = 0; i < 16; i++){
      int row = i * 4 + rq;
      float xx = xt[(size_t)row * N_ + col];
      float vv = v[i];
      vv = vv + (xx - vv) * 0.5f;
      bool sp = (vv - 1.0f) >= 0.0f;
      tile[row][col] = sp ? 0x3F80 : 0;
      v[i] = sp ? 0.0f : vv;
    }
    __syncthreads();
    char* otb = (char*)xsT + (size_t)(t * B_ + b) * 262144 + (size_t)ct * 2 * 16384;
#pragma unroll
    for (int p = 0; p < 2; p++){
      int nrow = p * 32 + (tid >> 3);
      int c0   = (tid & 7) * 8;                 // c-local 0..56
      int kkl  = c0 >> 5;                       // 0/1
      int slot = (c0 >> 3) & 3;
      int row  = nt * 64 + nrow;
      unsigned int w0 = (unsigned int)tile[c0 + 0][nrow] | ((unsigned int)tile[c0 + 1][nrow] << 16);
      unsigned int w1 = (unsigned int)tile[c0 + 2][nrow] | ((unsigned int)tile[c0 + 3][nrow] << 16);
      unsigned int w2 = (unsigned int)tile[c0 + 4][nrow] | ((unsigned int)tile[c0 + 5][nrow] << 16);
      unsigned int w3 = (unsigned int)tile[c0 + 6][nrow] | ((unsigned int)tile[c0 + 7][nrow] << 16);
      *(uint4*)(otb + kkl * 16384 + row * 64 + ((slot * 16) ^ swz32(row))) = uint4{w0, w1, w2, w3};
    }
    __syncthreads();
  }
}

// ---------------------------------------------------------------------------
// K2: q/k/v branch: y = W'.xs (+bias) -> LIF (vth=1) -> spikes.
// 512 threads (8 waves), wave tile [32o][64n]; BK=32 LDS double-buffer,
// prefetch-next-before-compute; all staging from contiguous slabs.
// q written [t,b,n,c]; k,v written [t,b,c,n].
// ---------------------------------------------------------------------------
__global__ __launch_bounds__(512, 2) void branch_kernel(
    const unsigned short* __restrict__ whi,
    const float* __restrict__ biasv, const unsigned short* __restrict__ xsT,
    unsigned short* __restrict__ qT, unsigned short* __restrict__ kS,
    unsigned short* __restrict__ vS)
{
  __shared__ alignas(16) unsigned short As[2][3 * 2048];   // 2 x 12KB
  __shared__ alignas(16) unsigned short Bs[2][8192];       // 2 x 16KB (also bounce)
  __shared__ alignas(16) float bias_lds[64];

  int bid = blockIdx.x;
  int b  = bid & 31;          // b fastest: blocks sharing b land on one XCD
  int r2 = bid >> 5;
  int ot = r2 & 7;
  int br = r2 >> 3;           // 0=q 1=k 2=v
  int o0 = ot * 64;
  int tid = threadIdx.x;
  int wv   = tid >> 6;        // wave 0..7
  int wr   = wv >> 2;         // o half (32 rows)
  int wc   = wv & 3;          // n quarter (64 cols)
  int lane = tid & 63;
  int lm = lane & 31;
  int hi = lane >> 5;

  if (tid < 64) bias_lds[tid] = biasv[br * 512 + o0 + tid];

  const unsigned short* wtile = whi + (size_t)(br * 8 + ot) * 32768;

  f32x16 acc[2];
  float  st[2][16];
#pragma unroll
  for (int c = 0; c < 2; c++)
#pragma unroll
    for (int i = 0; i < 16; i++) st[c][i] = 0.0f;

  for (int t = 0; t < T_; t++){
#pragma unroll
    for (int c = 0; c < 2; c++)
#pragma unroll
      for (int i = 0; i < 16; i++) acc[c][i] = 0.0f;

    const unsigned short* xslab = xsT + (size_t)(t * B_ + b) * 131072;

    stage_tiles(wtile, xslab, 0, tid, As[0], Bs[0]);
    __syncthreads();

    for (int kk = 0; kk < 16; kk++){            // K = 16 * 32
      int cur = kk & 1;
      if (kk < 15) stage_tiles(wtile, xslab, kk + 1, tid, As[cur ^ 1], Bs[cur ^ 1]);
#pragma unroll
      for (int ks = 0; ks < 2; ks++){
        int cb = ks * 32 + 16 * hi;
        bf16x8 b0 = frag32(Bs[cur], wc * 64 + lm,      cb);
        bf16x8 b1 = frag32(Bs[cur], wc * 64 + 32 + lm, cb);
        bf16x8 a0 = frag32(As[cur] + 0 * 2048, wr * 32 + lm, cb);
        acc[0] = __builtin_amdgcn_mfma_f32_32x32x16_bf16(a0, b0, acc[0], 0, 0, 0);
        acc[1] = __builtin_amdgcn_mfma_f32_32x32x16_bf16(a0, b1, acc[1], 0, 0, 0);
        bf16x8 a1 = frag32(As[cur] + 1 * 2048, wr * 32 + lm, cb);
        acc[0] = __builtin_amdgcn_mfma_f32_32x32x16_bf16(a1, b0, acc[0], 0, 0, 0);
        acc[1] = __builtin_amdgcn_mfma_f32_32x32x16_bf16(a1, b1, acc[1], 0, 0, 0);
        bf16x8 a2 = frag32(As[cur] + 2 * 2048, wr * 32 + lm, cb);
        acc[0] = __builtin_amdgcn_mfma_f32_32x32x16_bf16(a2, b0, acc[0], 0, 0, 0);
        acc[1] = __builtin_amdgcn_mfma_f32_32x32x16_bf16(a2, b1, acc[1], 0, 0, 0);
      }
      __syncthreads();                          // prefetch landed; reads done
    }

    // epilogue: bias + LIF -> spike bits into bounce (Bs region, 32KB)
    unsigned short* bounce = (unsigned short*)Bs;
#pragma unroll
    for (int nf = 0; nf < 2; nf++){
      int n_loc = wc * 64 + nf * 32 + lm;
#pragma unroll
      for (int rq = 0; rq < 4; rq++){
        float4_ b4 = *(const float4_*)&bias_lds[wr * 32 + 8 * rq + 4 * hi];
        unsigned short sb[4];
#pragma unroll
        for (int rr = 0; rr < 4; rr++){
          int r = rq * 4 + rr;
          float y = acc[nf][r] + b4[rr];
          float vvv = st[nf][r];
          vvv = vvv + (y - vvv) * 0.5f;
          bool sp = (vvv - 1.0f) >= 0.0f;
          st[nf][r] = sp ? 0.0f : vvv;
          sb[rr] = sp ? 0x3F80 : 0;
        }
        if (br == 0){   // q bounce: [n][64o] swizzled 128B rows, b64 pack
          unsigned int u0 = (unsigned int)sb[0] | ((unsigned int)sb[1] << 16);
          unsigned int u1 = (unsigned int)sb[2] | ((unsigned int)sb[3] << 16);
          int o0b = (wr * 32 + 8 * rq + 4 * hi) * 2;
          *(unsigned long long*)((char*)bounce + n_loc * 128 + (o0b ^ ((n_loc & 7) << 4)))
              = ((unsigned long long)u1 << 32) | u0;
        } else {        // k/v bounce: [64o][256n] linear
#pragma unroll
          for (int rr = 0; rr < 4; rr++){
            int o_loc = wr * 32 + rr + 8 * rq + 4 * hi;
            *(unsigned short*)((char*)bounce + o_loc * 512 + n_loc * 2) = sb[rr];
          }
        }
      }
    }
    __syncthreads();
    if (br == 0){
      unsigned short* dst = qT + (size_t)(t * B_ + b) * N_ * C_ + o0;
#pragma unroll
      for (int p = 0; p < 4; p++){
        int chunk = p * 512 + tid;
        int row = chunk >> 3, cbq = (chunk & 7) * 16;
        uint4 val = *(const uint4*)((const char*)bounce + row * 128 + (cbq ^ ((row & 7) << 4)));
        *(uint4*)((char*)dst + (size_t)row * 1024 + cbq) = val;
      }
    } else {
      unsigned short* dst = (br == 1 ? kS : vS) + ((size_t)(t * B_ + b) * C_ + o0) * N_;
#pragma unroll
      for (int p = 0; p < 4; p++){
        int chunk = p * 512 + tid;
        int row = chunk >> 5, nb = (chunk & 31) * 16;
        uint4 val = *(const uint4*)((const char*)bounce + row * 512 + nb);
        *(uint4*)((char*)dst + (size_t)row * 512 + nb) = val;
      }
    }
    __syncthreads();   // bounce reads done before next t's STAGE overwrites
  }
}

// ---------------------------------------------------------------------------
// K3: per (b,h): kv = K.V^T (exact integers), a = Q.kv * 0.125, attn LIF
// (vth=0.5, dyadic-exact) -> spikes into TILED sT slabs (proj's B layout).
// ---------------------------------------------------------------------------
__device__ __forceinline__ bf16x8 lds_frag(const unsigned short* base, int row, int cb){
  return *(const bf16x8*)((const char*)base + row * 128 + (cb ^ ((row & 7) << 4)));
}

__global__ __launch_bounds__(256, 2) void attn_kernel(
    const unsigned short* __restrict__ qT, const unsigned short* __restrict__ kS,
    const unsigned short* __restrict__ vS, unsigned short* __restrict__ sT)
{
  __shared__ alignas(16) unsigned short Ks[64 * 64];
  __shared__ alignas(16) unsigned short Vs[64 * 64];
  __shared__ alignas(16) unsigned short KVT[64 * 64];
  __shared__ alignas(16) unsigned short Qs[256 * 64];

  int bid = blockIdx.x;
  int b = bid & 31;
  int h = bid >> 5;
  int tid = threadIdx.x;
  int w = tid >> 6;
  int lane = tid & 63;
  int lm = lane & 31, hi = lane >> 5;
  int mfk = w >> 1, nfk = w & 1;

  float stA[2][2][16];
#pragma unroll
  for (int a = 0; a < 2; a++)
#pragma unroll
  for (int c = 0; c < 2; c++)
#pragma unroll
  for (int i = 0; i < 16; i++) stA[a][c][i] = 0.0f;

  for (int t = 0; t < T_; t++){
    const unsigned short* ksrc = kS + ((size_t)(t * B_ + b) * C_ + h * 64) * N_;
    const unsigned short* vsrc = vS + ((size_t)(t * B_ + b) * C_ + h * 64) * N_;
    const unsigned short* qsrc = qT + (size_t)(t * B_ + b) * N_ * C_ + h * 64;

    f32x16 kvacc;
#pragma unroll
    for (int i = 0; i < 16; i++) kvacc[i] = 0.0f;

    for (int ch = 0; ch < 4; ch++){
      __syncthreads();
#pragma unroll
      for (int p = 0; p < 2; p++){
        int chunk = p * 256 + tid;
        int row = chunk >> 3, cb = (chunk & 7) * 16;
        int so = (cb ^ ((row & 7) << 4));
        gload16((const char*)ksrc + (size_t)row * 512 + ch * 128 + so, (char*)Ks + chunk * 16);
        gload16((const char*)vsrc + (size_t)row * 512 + ch * 128 + so, (char*)Vs + chunk * 16);
      }
      __syncthreads();
#pragma unroll
      for (int ki = 0; ki < 4; ki++){
        int cb = ki * 32 + 16 * hi;
        bf16x8 ak = lds_frag(Ks, mfk * 32 + lm, cb);
        bf16x8 bv = lds_frag(Vs, nfk * 32 + lm, cb);
        kvacc = __builtin_amdgcn_mfma_f32_32x32x16_bf16(ak, bv, kvacc, 0, 0, 0);
      }
    }
    {
      int e = nfk * 32 + lm;
#pragma unroll
      for (int rq = 0; rq < 4; rq++){
        unsigned int u0 = (unsigned int)f2bf(kvacc[rq * 4 + 0])
                        | ((unsigned int)f2bf(kvacc[rq * 4 + 1]) << 16);
        unsigned int u1 = (unsigned int)f2bf(kvacc[rq * 4 + 2])
                        | ((unsigned int)f2bf(kvacc[rq * 4 + 3]) << 16);
        int d0b = (mfk * 32 + 8 * rq + 4 * hi) * 2;
        *(unsigned long long*)((char*)KVT + e * 128 + (d0b ^ ((e & 7) << 4)))
            = ((unsigned long long)u1 << 32) | u0;
      }
    }
#pragma unroll
    for (int p = 0; p < 8; p++){
      int chunk = p * 256 + tid;
      int row = chunk >> 3, cb = (chunk & 7) * 16;
      gload16((const char*)qsrc + (size_t)row * 1024 + (cb ^ ((row & 7) << 4)),
              (char*)Qs + chunk * 16);
    }
    __syncthreads();
    f32x16 aacc[2][2];
#pragma unroll
    for (int a = 0; a < 2; a++)
#pragma unroll
    for (int c = 0; c < 2; c++)
#pragma unroll
    for (int i = 0; i < 16; i++) aacc[a][c][i] = 0.0f;
#pragma unroll
    for (int ki = 0; ki < 4; ki++){
      int cb = ki * 32 + 16 * hi;
      bf16x8 aq0 = lds_frag(Qs, w * 64 + lm,      cb);
      bf16x8 aq1 = lds_frag(Qs, w * 64 + 32 + lm, cb);
      bf16x8 b0  = lds_frag(KVT, lm,      cb);
      bf16x8 b1  = lds_frag(KVT, 32 + lm, cb);
      aacc[0][0] = __builtin_amdgcn_mfma_f32_32x32x16_bf16(aq0, b0, aacc[0][0], 0, 0, 0);
      aacc[0][1] = __builtin_amdgcn_mfma_f32_32x32x16_bf16(aq0, b1, aacc[0][1], 0, 0, 0);
      aacc[1][0] = __builtin_amdgcn_mfma_f32_32x32x16_bf16(aq1, b0, aacc[1][0], 0, 0, 0);
      aacc[1][1] = __builtin_amdgcn_mfma_f32_32x32x16_bf16(aq1, b1, aacc[1][1], 0, 0, 0);
    }
#pragma unroll
    for (int mf = 0; mf < 2; mf++){
#pragma unroll
      for (int nf = 0; nf < 2; nf++){
        int e_loc = nf * 32 + lm;
#pragma unroll
        for (int r = 0; r < 16; r++){
          float aval = aacc[mf][nf][r] * 0.125f;
          float vvv = stA[mf][nf][r];
          vvv = vvv + (aval - vvv) * 0.5f;
          bool sp = (vvv - 0.5f) >= 0.0f;
          stA[mf][nf][r] = sp ? 0.0f : vvv;
          int n_loc = w * 64 + mf * 32 + (r & 3) + 8 * (r >> 2) + 4 * hi;
          *(unsigned short*)((char*)Qs + n_loc * 128 + ((e_loc * 2) ^ ((n_loc & 7) << 4))) = sp ? 0x3F80 : 0;
        }
      }
    }
    __syncthreads();
    // tiled s-write: slab kk = 2h + kkl, swizzled 64B rows (proj stages linearly)
    char* sbase = (char*)sT + (size_t)(t * B_ + b) * 262144 + (size_t)h * 2 * 16384;
#pragma unroll
    for (int p = 0; p < 8; p++){
      int chunk = p * 256 + tid;
      int row = chunk >> 3;
      int c0  = (chunk & 7) * 8;
      int kkl = c0 >> 5, slot = (c0 >> 3) & 3;
      uint4 val = *(const uint4*)((const char*)Qs + row * 128 + ((c0 * 2) ^ ((row & 7) << 4)));
      *(uint4*)(sbase + kkl * 16384 + row * 64 + ((slot * 16) ^ swz32(row))) = val;
    }
  }
}

// ---------------------------------------------------------------------------
// K4: projection: out = W'p . s + bias'p. Same 512-thread BK=32 dbuf template,
// contiguous slab staging.
// ---------------------------------------------------------------------------
__global__ __launch_bounds__(512, 2) void proj_kernel(
    const unsigned short* __restrict__ whi,
    const float* __restrict__ biasv, const unsigned short* __restrict__ sT,
    float* __restrict__ out)
{
  __shared__ alignas(16) unsigned short As[2][3 * 2048];
  __shared__ alignas(16) unsigned short Bs[2][8192];
  __shared__ alignas(16) float bias_lds[64];

  int bid = blockIdx.x;
  int tb = bid & 127;
  int ot = bid >> 7;
  int t = tb >> 5, b = tb & 31;
  int o0 = ot * 64;
  int tid = threadIdx.x;
  int wv = tid >> 6, wr = wv >> 2, wc = wv & 3;
  int lane = tid & 63, lm = lane & 31, hi = lane >> 5;

  if (tid < 64) bias_lds[tid] = biasv[3 * 512 + o0 + tid];

  const unsigned short* wtile = whi + (size_t)(24 + ot) * 32768;
  const unsigned short* bslab = sT + (size_t)(t * B_ + b) * 131072;

  f32x16 acc[2];
#pragma unroll
  for (int c = 0; c < 2; c++)
#pragma unroll
    for (int i = 0; i < 16; i++) acc[c][i] = 0.0f;

  stage_tiles(wtile, bslab, 0, tid, As[0], Bs[0]);
  __syncthreads();

  for (int kk = 0; kk < 16; kk++){
    int cur = kk & 1;
    if (kk < 15) stage_tiles(wtile, bslab, kk + 1, tid, As[cur ^ 1], Bs[cur ^ 1]);
#pragma unroll
    for (int ks = 0; ks < 2; ks++){
      int cb = ks * 32 + 16 * hi;
      bf16x8 b0 = frag32(Bs[cur], wc * 64 + lm,      cb);
      bf16x8 b1 = frag32(Bs[cur], wc * 64 + 32 + lm, cb);
      bf16x8 a0 = frag32(As[cur] + 0 * 2048, wr * 32 + lm, cb);
      acc[0] = __builtin_amdgcn_mfma_f32_32x32x16_bf16(a0, b0, acc[0], 0, 0, 0);
      acc[1] = __builtin_amdgcn_mfma_f32_32x32x16_bf16(a0, b1, acc[1], 0, 0, 0);
      bf16x8 a1 = frag32(As[cur] + 1 * 2048, wr * 32 + lm, cb);
      acc[0] = __builtin_amdgcn_mfma_f32_32x32x16_bf16(a1, b0, acc[0], 0, 0, 0);
      acc[1] = __builtin_amdgcn_mfma_f32_32x32x16_bf16(a1, b1, acc[1], 0, 0, 0);
      bf16x8 a2 = frag32(As[cur] + 2 * 2048, wr * 32 + lm, cb);
      acc[0] = __builtin_amdgcn_mfma_f32_32x32x16_bf16(a2, b0, acc[0], 0, 0, 0);
      acc[1] = __builtin_amdgcn_mfma_f32_32x32x16_bf16(a2, b1, acc[1], 0, 0, 0);
    }
    __syncthreads();
  }

  float* dst = out + ((size_t)(t * B_ + b) * C_ + o0) * N_;
#pragma unroll
  for (int nf = 0; nf < 2; nf++){
    int n_loc = wc * 64 + nf * 32 + lm;
#pragma unroll
    for (int rq = 0; rq < 4; rq++){
      float4_ b4 = *(const float4_*)&bias_lds[wr * 32 + 8 * rq + 4 * hi];
#pragma unroll
      for (int rr = 0; rr < 4; rr++){
        int o_loc = wr * 32 + rr + 8 * rq + 4 * hi;
        dst[(size_t)o_loc * N_ + n_loc] = acc[nf][rq * 4 + rr] + b4[rr];
      }
    }
  }
}

// ---------------------------------------------------------------------------
// launch
// ---------------------------------------------------------------------------
extern "C" void kernel_launch(void* const* d_in, const int* in_sizes, int n_in,
                              void* d_out, int out_size, void* d_ws, size_t ws_size,
                              hipStream_t stream) {
  const float* x = (const float*)d_in[0];
  PrepArgs pa;
  pa.w[0]  = (const float*)d_in[1];
  pa.g[0]  = (const float*)d_in[2];
  pa.bb[0] = (const float*)d_in[3];
  pa.m[0]  = (const float*)d_in[4];
  pa.v[0]  = (const float*)d_in[5];
  pa.w[1]  = (const float*)d_in[6];
  pa.g[1]  = (const float*)d_in[7];
  pa.bb[1] = (const float*)d_in[8];
  pa.m[1]  = (const float*)d_in[9];
  pa.v[1]  = (const float*)d_in[10];
  pa.w[2]  = (const float*)d_in[11];
  pa.g[2]  = (const float*)d_in[12];
  pa.bb[2] = (const float*)d_in[13];
  pa.m[2]  = (const float*)d_in[14];
  pa.v[2]  = (const float*)d_in[15];
  pa.w[3]  = (const float*)d_in[16];
  pa.pbias = (const float*)d_in[17];
  pa.g[3]  = (const float*)d_in[18];
  pa.bb[3] = (const float*)d_in[19];
  pa.m[3]  = (const float*)d_in[20];
  pa.v[3]  = (const float*)d_in[21];

  // workspace layout (~140 MB). whi/wmid/wlo MUST stay 0x200000 bytes apart
  // (stage_tiles derives term pointers arithmetically).
  char* ws = (char*)d_ws;
  unsigned short* whi  = (unsigned short*)(ws);                               // 2 MB slabs
  unsigned short* wmid = (unsigned short*)(ws + 0x200000);                    // 2 MB
  unsigned short* wlo  = (unsigned short*)(ws + 0x400000);                    // 2 MB
  float*          biasv= (float*)(ws + 0x600000);                             // 8 KB
  unsigned short* xsT  = (unsigned short*)(ws + 0x610000);                    // 32 MiB tiled slabs
  unsigned short* sTp  = xsT;                                                 // alias: xs dead before s written
  unsigned short* qT   = (unsigned short*)(ws + 0x610000 + (size_t)32*1024*1024);
  unsigned short* kS   = (unsigned short*)(ws + 0x610000 + (size_t)64*1024*1024);
  unsigned short* vS   = (unsigned short*)(ws + 0x610000 + (size_t)96*1024*1024);

  prep_kernel<<<512, 256, 0, stream>>>(pa, whi, wmid, wlo, biasv);
  lif_tr_kernel<<<1024, 256, 0, stream>>>(x, xsT);
  branch_kernel<<<768, 512, 0, stream>>>(whi, biasv, xsT, qT, kS, vS);
  attn_kernel<<<256, 256, 0, stream>>>(qT, kS, vS, sTp);
  proj_kernel<<<1024, 512, 0, stream>>>(whi, biasv, sTp, (float*)d_out);
}